// Round 4
// baseline (1192.812 us; speedup 1.0000x reference)
//
#include <hip/hip_runtime.h>

#define NN  100000
#define NE  640000
#define DIM 128
#define NPT 32   // nodes per finalize tile
#define PAD 4    // LDS row pad: stride (DIM+PAD)*4 = 528 B, 16B-aligned

// ---------------------------------------------------------------------------
// Scatter: 32 lanes per edge, each lane handles 4 floats (float4 gather),
// atomicAdd into agg (= d_out). Lane 0 bumps the target's count.
// NOTE: harness delivers integer inputs as int32 (NOT the reference's int64).
// ---------------------------------------------------------------------------
__global__ __launch_bounds__(256) void scatter_k(
    const float* __restrict__ x,
    const int* __restrict__ ei,         // [2][NE] int32: src row then tgt row
    float* __restrict__ agg,            // [NN][DIM], pre-zeroed (aliased d_out)
    float* __restrict__ counts)         // [NN], pre-zeroed (ws)
{
    int gid  = blockIdx.x * 256 + threadIdx.x;
    int e    = gid >> 5;
    int lane = gid & 31;
    if (e >= NE) return;
    int s = ei[e];
    int t = ei[NE + e];
    if ((unsigned)s >= NN || (unsigned)t >= NN) return;  // guard: fault -> mismatch
    float4 v = *reinterpret_cast<const float4*>(x + (size_t)s * DIM + lane * 4);
    float* a = agg + (size_t)t * DIM + lane * 4;
    atomicAdd(a + 0, v.x);
    atomicAdd(a + 1, v.y);
    atomicAdd(a + 2, v.z);
    atomicAdd(a + 3, v.w);
    if (lane == 0) atomicAdd(counts + t, 1.0f);
}

// ---------------------------------------------------------------------------
// Finalize: out[n] = x[n] + b + (agg[n]/max(cnt,1)) @ W^T
// LDS < 64 KB: W staged transposed in TWO 64-wide chunks (Ws[64][132] =
// 33.8 KB) + 32 mean rows (mean_s[32][132] = 16.9 KB) -> 50.7 KB.
// Row stride 528 B keeps all float4 LDS accesses 16B-aligned.
// agg read from `out`, overwritten in place (same rows, same block, after
// __syncthreads -> no hazard).
// ---------------------------------------------------------------------------
__global__ __launch_bounds__(256) void finalize_k(
    const float* __restrict__ x,
    const float* __restrict__ W,        // [o][i] row-major, 128x128
    const float* __restrict__ b,
    const float* __restrict__ counts,
    float* __restrict__ out)            // in: agg ; out: result
{
    __shared__ float Ws[64][DIM + PAD];       // Ws[il][o] = W[o][c*64+il]
    __shared__ float mean_s[NPT][DIM + PAD];

    const int t    = threadIdx.x;
    const int base = blockIdx.x * NPT;

    // Stage 32 mean rows: 8 threads per node, 16 floats each (coalesced)
    {
        int sn   = t >> 3;
        int so   = (t & 7) * 16;
        int node = base + sn;
        float inv = 1.0f / fmaxf(counts[node], 1.0f);
        const float4* ar = reinterpret_cast<const float4*>(out + (size_t)node * DIM + so);
        #pragma unroll
        for (int k = 0; k < 4; ++k) {
            float4 m = ar[k];
            m.x *= inv; m.y *= inv; m.z *= inv; m.w *= inv;
            *reinterpret_cast<float4*>(&mean_s[sn][so + 4 * k]) = m;
        }
    }

    const int og = (t & 31) * 4;    // 4 consecutive outputs per thread
    const int ng = (t >> 5) * 4;    // 4 consecutive nodes per thread

    float4 acc[4];
    #pragma unroll
    for (int n = 0; n < 4; ++n) acc[n] = make_float4(0.f, 0.f, 0.f, 0.f);

    for (int c = 0; c < 2; ++c) {
        __syncthreads();   // (c=0: also covers mean_s staging)
        // Stage W chunk transposed: 8192 elements, coalesced global reads
        #pragma unroll
        for (int k = 0; k < 32; ++k) {
            int idx = t + k * 256;      // 0..8191
            int o   = idx >> 6;         // 0..127
            int il  = idx & 63;         // 0..63
            Ws[il][o] = W[o * DIM + c * 64 + il];
        }
        __syncthreads();

        #pragma unroll
        for (int i = 0; i < 64; i += 4) {
            float4 m4[4];
            #pragma unroll
            for (int n = 0; n < 4; ++n)
                m4[n] = *reinterpret_cast<const float4*>(&mean_s[ng + n][c * 64 + i]);
            #pragma unroll
            for (int j = 0; j < 4; ++j) {
                float4 w = *reinterpret_cast<const float4*>(&Ws[i + j][og]);
                #pragma unroll
                for (int n = 0; n < 4; ++n) {
                    float m = (j == 0) ? m4[n].x : (j == 1) ? m4[n].y
                            : (j == 2) ? m4[n].z : m4[n].w;
                    acc[n].x += m * w.x;
                    acc[n].y += m * w.y;
                    acc[n].z += m * w.z;
                    acc[n].w += m * w.w;
                }
            }
        }
    }

    float4 bv = *reinterpret_cast<const float4*>(b + og);
    #pragma unroll
    for (int n = 0; n < 4; ++n) {
        int node = base + ng + n;
        float4 xv = *reinterpret_cast<const float4*>(x + (size_t)node * DIM + og);
        float4 o4;
        o4.x = xv.x + bv.x + acc[n].x;
        o4.y = xv.y + bv.y + acc[n].y;
        o4.z = xv.z + bv.z + acc[n].z;
        o4.w = xv.w + bv.w + acc[n].w;
        *reinterpret_cast<float4*>(out + (size_t)node * DIM + og) = o4;
    }
}

extern "C" void kernel_launch(void* const* d_in, const int* in_sizes, int n_in,
                              void* d_out, int out_size, void* d_ws, size_t ws_size,
                              hipStream_t stream) {
    const float* x  = (const float*)d_in[0];
    const int*   ei = (const int*)d_in[1];     // int32 per harness contract
    const float* W  = (const float*)d_in[2];
    const float* b  = (const float*)d_in[3];
    float* out    = (float*)d_out;
    float* counts = (float*)d_ws;   // needs NN*4 = 400 KB of ws

    // Zero agg (aliased with d_out) and counts
    hipMemsetAsync(d_out, 0, (size_t)NN * DIM * sizeof(float), stream);
    hipMemsetAsync(counts, 0, (size_t)NN * sizeof(float), stream);

    // 32 threads per edge -> NE*32 threads
    scatter_k<<<(NE * 32) / 256, 256, 0, stream>>>(x, ei, out, counts);

    // 32 nodes per block -> NN/32 = 3125 blocks (exact)
    finalize_k<<<NN / NPT, 256, 0, stream>>>(x, W, b, counts, out);
}

// Round 5
// 418.778 us; speedup vs baseline: 2.8483x; 2.8483x over previous
//
#include <hip/hip_runtime.h>

#define NN  100000
#define NE  640000
#define DIM 128
#define NPT 32   // nodes per finalize tile
#define PAD 4    // LDS row pad: stride 528 B, 16B-aligned
#define SCAN_T 1024
#define CHUNK  98   // ceil(NN / SCAN_T)

// ws layout (all 4-byte elems), total 3*NN+2+NE = 940002 elems ~= 3.76 MB:
//   cnts [0, NN)  offs [NN, 2NN+1)  curs [2NN+2, 3NN+2)  esrc [3NN+2, +NE)

// ---------------------------------------------------------------------------
// 1) Histogram of targets: 640K int atomics on 100K counters (avg 6.4 hits).
// ---------------------------------------------------------------------------
__global__ __launch_bounds__(256) void hist_k(
    const int* __restrict__ ei, unsigned* __restrict__ cnts)
{
    int e = blockIdx.x * 256 + threadIdx.x;
    if (e >= NE) return;
    int t = ei[NE + e];
    if ((unsigned)t >= NN) return;
    atomicAdd(&cnts[t], 1u);
}

// ---------------------------------------------------------------------------
// 2) Single-block exclusive scan of cnts -> offs, and offs -> curs copy.
//    1024 threads, 98 elements each: serial chunk sums + Hillis-Steele block
//    scan + serial chunk writeback.
// ---------------------------------------------------------------------------
__global__ __launch_bounds__(SCAN_T) void scan_k(
    const unsigned* __restrict__ cnts,
    unsigned* __restrict__ offs,     // [NN+1]
    unsigned* __restrict__ curs)     // [NN]
{
    __shared__ unsigned ps[SCAN_T];
    const int t   = threadIdx.x;
    const int beg = t * CHUNK;
    const int end = min(beg + CHUNK, NN);

    unsigned sum = 0;
    for (int i = beg; i < end; ++i) sum += cnts[i];
    ps[t] = sum;
    __syncthreads();

    // inclusive scan over 1024 partials
    for (int off = 1; off < SCAN_T; off <<= 1) {
        unsigned v = (t >= off) ? ps[t - off] : 0u;
        __syncthreads();
        ps[t] += v;
        __syncthreads();
    }

    unsigned run = (t == 0) ? 0u : ps[t - 1];
    for (int i = beg; i < end; ++i) {
        offs[i] = run;
        curs[i] = run;
        run += cnts[i];
    }
    if (t == SCAN_T - 1) offs[NN] = run;   // == total binned edges
}

// ---------------------------------------------------------------------------
// 3) Bin edges by target: esrc[slot] = src. 640K int atomics on cursors.
// ---------------------------------------------------------------------------
__global__ __launch_bounds__(256) void bin_k(
    const int* __restrict__ ei,
    unsigned* __restrict__ curs,
    int* __restrict__ esrc)
{
    int e = blockIdx.x * 256 + threadIdx.x;
    if (e >= NE) return;
    int s = ei[e];
    int t = ei[NE + e];
    if ((unsigned)s >= NN || (unsigned)t >= NN) return;
    unsigned pos = atomicAdd(&curs[t], 1u);
    esrc[pos] = s;
}

// ---------------------------------------------------------------------------
// 4) Gather-side reduction: one half-wave (32 lanes x float4) per node.
//    Sums x[src] rows over the node's CSR segment, writes the MEAN row.
//    Every node row is written (empty segment -> zeros), so no d_out memset.
// ---------------------------------------------------------------------------
__global__ __launch_bounds__(256) void reduce_k(
    const float* __restrict__ x,
    const unsigned* __restrict__ offs,
    const int* __restrict__ esrc,
    float* __restrict__ out)            // mean rows [NN][DIM]
{
    const int lane = threadIdx.x & 31;
    const int n    = blockIdx.x * 8 + (threadIdx.x >> 5);
    unsigned beg = offs[n], end = offs[n + 1];

    float4 v = make_float4(0.f, 0.f, 0.f, 0.f);
    for (unsigned j = beg; j < end; ++j) {
        int s = esrc[j];
        float4 g = *reinterpret_cast<const float4*>(x + (size_t)s * DIM + lane * 4);
        v.x += g.x; v.y += g.y; v.z += g.z; v.w += g.w;
    }
    float inv = 1.0f / fmaxf((float)(end - beg), 1.0f);
    v.x *= inv; v.y *= inv; v.z *= inv; v.w *= inv;
    *reinterpret_cast<float4*>(out + (size_t)n * DIM + lane * 4) = v;
}

// ---------------------------------------------------------------------------
// 5) Finalize: out[n] = x[n] + b + mean[n] @ W^T   (mean already divided)
//    W staged transposed in two 64-wide chunks; 50.7 KB LDS total.
// ---------------------------------------------------------------------------
__global__ __launch_bounds__(256) void finalize_k(
    const float* __restrict__ x,
    const float* __restrict__ W,        // [o][i] row-major, 128x128
    const float* __restrict__ b,
    float* __restrict__ out)            // in: mean ; out: result
{
    __shared__ float Ws[64][DIM + PAD];       // Ws[il][o] = W[o][c*64+il]
    __shared__ float mean_s[NPT][DIM + PAD];

    const int t    = threadIdx.x;
    const int base = blockIdx.x * NPT;

    // Stage 32 mean rows: 8 threads per node, 16 floats each (coalesced)
    {
        int sn   = t >> 3;
        int so   = (t & 7) * 16;
        int node = base + sn;
        const float4* ar = reinterpret_cast<const float4*>(out + (size_t)node * DIM + so);
        #pragma unroll
        for (int k = 0; k < 4; ++k)
            *reinterpret_cast<float4*>(&mean_s[sn][so + 4 * k]) = ar[k];
    }

    const int og = (t & 31) * 4;    // 4 consecutive outputs per thread
    const int ng = (t >> 5) * 4;    // 4 consecutive nodes per thread

    float4 acc[4];
    #pragma unroll
    for (int n = 0; n < 4; ++n) acc[n] = make_float4(0.f, 0.f, 0.f, 0.f);

    for (int c = 0; c < 2; ++c) {
        __syncthreads();   // (c=0: also covers mean_s staging)
        #pragma unroll
        for (int k = 0; k < 32; ++k) {
            int idx = t + k * 256;      // 0..8191
            int o   = idx >> 6;
            int il  = idx & 63;
            Ws[il][o] = W[o * DIM + c * 64 + il];
        }
        __syncthreads();

        #pragma unroll
        for (int i = 0; i < 64; i += 4) {
            float4 m4[4];
            #pragma unroll
            for (int n = 0; n < 4; ++n)
                m4[n] = *reinterpret_cast<const float4*>(&mean_s[ng + n][c * 64 + i]);
            #pragma unroll
            for (int j = 0; j < 4; ++j) {
                float4 w = *reinterpret_cast<const float4*>(&Ws[i + j][og]);
                #pragma unroll
                for (int n = 0; n < 4; ++n) {
                    float m = (j == 0) ? m4[n].x : (j == 1) ? m4[n].y
                            : (j == 2) ? m4[n].z : m4[n].w;
                    acc[n].x += m * w.x;
                    acc[n].y += m * w.y;
                    acc[n].z += m * w.z;
                    acc[n].w += m * w.w;
                }
            }
        }
    }

    float4 bv = *reinterpret_cast<const float4*>(b + og);
    #pragma unroll
    for (int n = 0; n < 4; ++n) {
        int node = base + ng + n;
        float4 xv = *reinterpret_cast<const float4*>(x + (size_t)node * DIM + og);
        float4 o4;
        o4.x = xv.x + bv.x + acc[n].x;
        o4.y = xv.y + bv.y + acc[n].y;
        o4.z = xv.z + bv.z + acc[n].z;
        o4.w = xv.w + bv.w + acc[n].w;
        *reinterpret_cast<float4*>(out + (size_t)node * DIM + og) = o4;
    }
}

extern "C" void kernel_launch(void* const* d_in, const int* in_sizes, int n_in,
                              void* d_out, int out_size, void* d_ws, size_t ws_size,
                              hipStream_t stream) {
    const float* x  = (const float*)d_in[0];
    const int*   ei = (const int*)d_in[1];     // int32 per harness contract
    const float* W  = (const float*)d_in[2];
    const float* b  = (const float*)d_in[3];
    float* out = (float*)d_out;

    unsigned* cnts = (unsigned*)d_ws;
    unsigned* offs = cnts + NN;          // NN+1
    unsigned* curs = cnts + 2 * NN + 2;  // NN
    int*      esrc = (int*)(cnts + 3 * NN + 2);  // NE

    hipMemsetAsync(cnts, 0, (size_t)NN * sizeof(unsigned), stream);

    hist_k  <<<(NE + 255) / 256, 256, 0, stream>>>(ei, cnts);
    scan_k  <<<1, SCAN_T, 0, stream>>>(cnts, offs, curs);
    bin_k   <<<(NE + 255) / 256, 256, 0, stream>>>(ei, curs, esrc);
    reduce_k<<<NN / 8, 256, 0, stream>>>(x, offs, esrc, out);
    finalize_k<<<NN / NPT, 256, 0, stream>>>(x, W, b, out);
}

// Round 6
// 195.312 us; speedup vs baseline: 6.1072x; 2.1442x over previous
//
#include <hip/hip_runtime.h>

#define NN    100000
#define NE    640000
#define DIM   128
#define NPT   32    // nodes per fused tile
#define PAD   4     // LDS row pad: stride 528 B, 16B-aligned
#define TILE  1024  // scan tile (elements per block)
#define NBLK  98    // ceil(NN / TILE)

// ws layout (4-byte elems), 16B-aligned sections:
//   cnts [0, NN)          offs [NN, 2NN+4)       (NN+1 used)
//   curs [2NN+4, 3NN+4)   esrc [3NN+4, 3NN+4+NE)
//   blksum [+128]         blkoff [+128]          total ~3.77 MB

// ---------------------------------------------------------------------------
// 1) Histogram of targets: 640K int atomics on 100K counters.
// ---------------------------------------------------------------------------
__global__ __launch_bounds__(256) void hist_k(
    const int* __restrict__ ei, unsigned* __restrict__ cnts)
{
    int e = blockIdx.x * 256 + threadIdx.x;
    if (e >= NE) return;
    int t = ei[NE + e];
    if ((unsigned)t >= NN) return;
    atomicAdd(&cnts[t], 1u);
}

// ---------------------------------------------------------------------------
// 2a) Per-block sums of 1024-elem tiles (uint4 loads, shuffle reduce).
// ---------------------------------------------------------------------------
__global__ __launch_bounds__(256) void scan_a_k(
    const unsigned* __restrict__ cnts, unsigned* __restrict__ blksum)
{
    __shared__ unsigned red[4];
    int t    = threadIdx.x;
    int base = blockIdx.x * TILE + t * 4;
    unsigned v = 0;
    if (base + 3 < NN) {
        uint4 u = *reinterpret_cast<const uint4*>(cnts + base);
        v = u.x + u.y + u.z + u.w;
    } else {
        for (int k = 0; k < 4; ++k) if (base + k < NN) v += cnts[base + k];
    }
    #pragma unroll
    for (int off = 32; off; off >>= 1) v += __shfl_down(v, off);
    if ((t & 63) == 0) red[t >> 6] = v;
    __syncthreads();
    if (t == 0) blksum[blockIdx.x] = red[0] + red[1] + red[2] + red[3];
}

// ---------------------------------------------------------------------------
// 2b) Single-block scan of the 98 block sums -> exclusive block offsets.
// ---------------------------------------------------------------------------
__global__ __launch_bounds__(128) void scan_b_k(
    const unsigned* __restrict__ blksum,
    unsigned* __restrict__ blkoff,
    unsigned* __restrict__ offs)
{
    __shared__ unsigned ps[128];
    int t = threadIdx.x;
    ps[t] = (t < NBLK) ? blksum[t] : 0u;
    __syncthreads();
    for (int off = 1; off < 128; off <<= 1) {
        unsigned u = (t >= off) ? ps[t - off] : 0u;
        __syncthreads();
        ps[t] += u;
        __syncthreads();
    }
    if (t < NBLK) blkoff[t] = (t == 0) ? 0u : ps[t - 1];
    if (t == 0)   offs[NN]  = ps[NBLK - 1];   // total binned edges
}

// ---------------------------------------------------------------------------
// 2c) Per-block exclusive scan + block offset -> offs, curs (uint4 stores).
// ---------------------------------------------------------------------------
__global__ __launch_bounds__(256) void scan_c_k(
    const unsigned* __restrict__ cnts,
    const unsigned* __restrict__ blkoff,
    unsigned* __restrict__ offs,
    unsigned* __restrict__ curs)
{
    __shared__ unsigned ps[256];
    int t    = threadIdx.x;
    int base = blockIdx.x * TILE + t * 4;
    unsigned v0 = 0, v1 = 0, v2 = 0, v3 = 0;
    if (base + 3 < NN) {
        uint4 u = *reinterpret_cast<const uint4*>(cnts + base);
        v0 = u.x; v1 = u.y; v2 = u.z; v3 = u.w;
    } else {
        if (base     < NN) v0 = cnts[base];
        if (base + 1 < NN) v1 = cnts[base + 1];
        if (base + 2 < NN) v2 = cnts[base + 2];
    }
    ps[t] = v0 + v1 + v2 + v3;
    __syncthreads();
    for (int off = 1; off < 256; off <<= 1) {
        unsigned u = (t >= off) ? ps[t - off] : 0u;
        __syncthreads();
        ps[t] += u;
        __syncthreads();
    }
    unsigned run = blkoff[blockIdx.x] + ((t == 0) ? 0u : ps[t - 1]);
    unsigned o0 = run, o1 = o0 + v0, o2 = o1 + v1, o3 = o2 + v2;
    if (base + 3 < NN) {
        *reinterpret_cast<uint4*>(offs + base) = make_uint4(o0, o1, o2, o3);
        *reinterpret_cast<uint4*>(curs + base) = make_uint4(o0, o1, o2, o3);
    } else {
        if (base     < NN) { offs[base]     = o0; curs[base]     = o0; }
        if (base + 1 < NN) { offs[base + 1] = o1; curs[base + 1] = o1; }
        if (base + 2 < NN) { offs[base + 2] = o2; curs[base + 2] = o2; }
    }
}

// ---------------------------------------------------------------------------
// 3) Bin edges by target: esrc[slot] = src.
// ---------------------------------------------------------------------------
__global__ __launch_bounds__(256) void bin_k(
    const int* __restrict__ ei,
    unsigned* __restrict__ curs,
    int* __restrict__ esrc)
{
    int e = blockIdx.x * 256 + threadIdx.x;
    if (e >= NE) return;
    int s = ei[e];
    int t = ei[NE + e];
    if ((unsigned)s >= NN || (unsigned)t >= NN) return;
    unsigned pos = atomicAdd(&curs[t], 1u);
    esrc[pos] = s;
}

// ---------------------------------------------------------------------------
// 4) Fused mean + linear + residual:
//    out[n] = x[n] + b + (mean over CSR segment of x[src]) @ W^T
//    Mean computed straight into LDS (8 threads/node, 16 floats each,
//    x is L3-resident). W staged transposed in two 64-wide chunks.
//    LDS: Ws[64][132] 33.8 KB + mean_s[32][132] 16.9 KB = 50.7 KB.
// ---------------------------------------------------------------------------
__global__ __launch_bounds__(256) void fused_k(
    const float* __restrict__ x,
    const float* __restrict__ W,        // [o][i] row-major, 128x128
    const float* __restrict__ b,
    const unsigned* __restrict__ offs,
    const int* __restrict__ esrc,
    float* __restrict__ out)
{
    __shared__ float Ws[64][DIM + PAD];       // Ws[il][o] = W[o][c*64+il]
    __shared__ float mean_s[NPT][DIM + PAD];

    const int t    = threadIdx.x;
    const int base = blockIdx.x * NPT;

    // Compute 32 mean rows directly: 8 threads/node, 16 floats each.
    {
        int sn   = t >> 3;
        int so   = (t & 7) * 16;
        int node = base + sn;
        unsigned beg = offs[node], end = offs[node + 1];
        float4 a0 = make_float4(0.f, 0.f, 0.f, 0.f), a1 = a0, a2 = a0, a3 = a0;
        for (unsigned j = beg; j < end; ++j) {
            int s = esrc[j];
            const float4* xr = reinterpret_cast<const float4*>(x + (size_t)s * DIM + so);
            float4 g0 = xr[0], g1 = xr[1], g2 = xr[2], g3 = xr[3];
            a0.x += g0.x; a0.y += g0.y; a0.z += g0.z; a0.w += g0.w;
            a1.x += g1.x; a1.y += g1.y; a1.z += g1.z; a1.w += g1.w;
            a2.x += g2.x; a2.y += g2.y; a2.z += g2.z; a2.w += g2.w;
            a3.x += g3.x; a3.y += g3.y; a3.z += g3.z; a3.w += g3.w;
        }
        float inv = 1.0f / fmaxf((float)(end - beg), 1.0f);
        a0.x *= inv; a0.y *= inv; a0.z *= inv; a0.w *= inv;
        a1.x *= inv; a1.y *= inv; a1.z *= inv; a1.w *= inv;
        a2.x *= inv; a2.y *= inv; a2.z *= inv; a2.w *= inv;
        a3.x *= inv; a3.y *= inv; a3.z *= inv; a3.w *= inv;
        *reinterpret_cast<float4*>(&mean_s[sn][so +  0]) = a0;
        *reinterpret_cast<float4*>(&mean_s[sn][so +  4]) = a1;
        *reinterpret_cast<float4*>(&mean_s[sn][so +  8]) = a2;
        *reinterpret_cast<float4*>(&mean_s[sn][so + 12]) = a3;
    }

    const int og = (t & 31) * 4;    // 4 consecutive outputs per thread
    const int ng = (t >> 5) * 4;    // 4 consecutive nodes per thread

    float4 acc[4];
    #pragma unroll
    for (int n = 0; n < 4; ++n) acc[n] = make_float4(0.f, 0.f, 0.f, 0.f);

    for (int c = 0; c < 2; ++c) {
        __syncthreads();   // (c=0: also covers mean_s staging)
        #pragma unroll
        for (int k = 0; k < 32; ++k) {
            int idx = t + k * 256;      // 0..8191
            int o   = idx >> 6;
            int il  = idx & 63;
            Ws[il][o] = W[o * DIM + c * 64 + il];
        }
        __syncthreads();

        #pragma unroll
        for (int i = 0; i < 64; i += 4) {
            float4 m4[4];
            #pragma unroll
            for (int n = 0; n < 4; ++n)
                m4[n] = *reinterpret_cast<const float4*>(&mean_s[ng + n][c * 64 + i]);
            #pragma unroll
            for (int j = 0; j < 4; ++j) {
                float4 w = *reinterpret_cast<const float4*>(&Ws[i + j][og]);
                #pragma unroll
                for (int n = 0; n < 4; ++n) {
                    float m = (j == 0) ? m4[n].x : (j == 1) ? m4[n].y
                            : (j == 2) ? m4[n].z : m4[n].w;
                    acc[n].x += m * w.x;
                    acc[n].y += m * w.y;
                    acc[n].z += m * w.z;
                    acc[n].w += m * w.w;
                }
            }
        }
    }

    float4 bv = *reinterpret_cast<const float4*>(b + og);
    #pragma unroll
    for (int n = 0; n < 4; ++n) {
        int node = base + ng + n;
        float4 xv = *reinterpret_cast<const float4*>(x + (size_t)node * DIM + og);
        float4 o4;
        o4.x = xv.x + bv.x + acc[n].x;
        o4.y = xv.y + bv.y + acc[n].y;
        o4.z = xv.z + bv.z + acc[n].z;
        o4.w = xv.w + bv.w + acc[n].w;
        *reinterpret_cast<float4*>(out + (size_t)node * DIM + og) = o4;
    }
}

extern "C" void kernel_launch(void* const* d_in, const int* in_sizes, int n_in,
                              void* d_out, int out_size, void* d_ws, size_t ws_size,
                              hipStream_t stream) {
    const float* x  = (const float*)d_in[0];
    const int*   ei = (const int*)d_in[1];     // int32 per harness contract
    const float* W  = (const float*)d_in[2];
    const float* b  = (const float*)d_in[3];
    float* out = (float*)d_out;

    unsigned* cnts   = (unsigned*)d_ws;
    unsigned* offs   = cnts + NN;              // NN+1 used (padded to NN+4)
    unsigned* curs   = cnts + 2 * NN + 4;      // NN
    int*      esrc   = (int*)(cnts + 3 * NN + 4);   // NE
    unsigned* blksum = (unsigned*)(esrc + NE);      // 128
    unsigned* blkoff = blksum + 128;                // 128

    hipMemsetAsync(cnts, 0, (size_t)NN * sizeof(unsigned), stream);

    hist_k  <<<(NE + 255) / 256, 256, 0, stream>>>(ei, cnts);
    scan_a_k<<<NBLK, 256, 0, stream>>>(cnts, blksum);
    scan_b_k<<<1, 128, 0, stream>>>(blksum, blkoff, offs);
    scan_c_k<<<NBLK, 256, 0, stream>>>(cnts, blkoff, offs, curs);
    bin_k   <<<(NE + 255) / 256, 256, 0, stream>>>(ei, curs, esrc);
    fused_k <<<NN / NPT, 256, 0, stream>>>(x, W, b, offs, esrc, out);
}

// Round 7
// 168.330 us; speedup vs baseline: 7.0861x; 1.1603x over previous
//
#include <hip/hip_runtime.h>

#define NN    100000
#define NE    640000
#define DIM   128
#define NPT   32    // nodes per fused tile
#define PAD   4     // LDS row pad: stride 528 B, 16B-aligned
#define WCH   32    // W chunk width (inner-dim) -> Ws 16.9 KB, 4 chunks
#define TILE  1024  // scan tile (elements per block)
#define NBLK  98    // ceil(NN / TILE)

// ws layout (4-byte elems), 16B-aligned sections:
//   cnts [0, NN)          offs [NN, 2NN+4)       (NN+1 used)
//   curs [2NN+4, 3NN+4)   esrc [3NN+4, 3NN+4+NE)
//   blksum [+128]         blkoff [+128]          total ~3.77 MB

// ---------------------------------------------------------------------------
// 1) Histogram of targets: 640K int atomics on 100K counters.
// ---------------------------------------------------------------------------
__global__ __launch_bounds__(256) void hist_k(
    const int* __restrict__ ei, unsigned* __restrict__ cnts)
{
    int e = blockIdx.x * 256 + threadIdx.x;
    if (e >= NE) return;
    int t = ei[NE + e];
    if ((unsigned)t >= NN) return;
    atomicAdd(&cnts[t], 1u);
}

// ---------------------------------------------------------------------------
// 2a) Per-block sums of 1024-elem tiles (uint4 loads, shuffle reduce).
// ---------------------------------------------------------------------------
__global__ __launch_bounds__(256) void scan_a_k(
    const unsigned* __restrict__ cnts, unsigned* __restrict__ blksum)
{
    __shared__ unsigned red[4];
    int t    = threadIdx.x;
    int base = blockIdx.x * TILE + t * 4;
    unsigned v = 0;
    if (base + 3 < NN) {
        uint4 u = *reinterpret_cast<const uint4*>(cnts + base);
        v = u.x + u.y + u.z + u.w;
    } else {
        for (int k = 0; k < 4; ++k) if (base + k < NN) v += cnts[base + k];
    }
    #pragma unroll
    for (int off = 32; off; off >>= 1) v += __shfl_down(v, off);
    if ((t & 63) == 0) red[t >> 6] = v;
    __syncthreads();
    if (t == 0) blksum[blockIdx.x] = red[0] + red[1] + red[2] + red[3];
}

// ---------------------------------------------------------------------------
// 2b) Single-block scan of the 98 block sums -> exclusive block offsets.
// ---------------------------------------------------------------------------
__global__ __launch_bounds__(128) void scan_b_k(
    const unsigned* __restrict__ blksum,
    unsigned* __restrict__ blkoff,
    unsigned* __restrict__ offs)
{
    __shared__ unsigned ps[128];
    int t = threadIdx.x;
    ps[t] = (t < NBLK) ? blksum[t] : 0u;
    __syncthreads();
    for (int off = 1; off < 128; off <<= 1) {
        unsigned u = (t >= off) ? ps[t - off] : 0u;
        __syncthreads();
        ps[t] += u;
        __syncthreads();
    }
    if (t < NBLK) blkoff[t] = (t == 0) ? 0u : ps[t - 1];
    if (t == 0)   offs[NN]  = ps[NBLK - 1];   // total binned edges
}

// ---------------------------------------------------------------------------
// 2c) Per-block exclusive scan + block offset -> offs, curs (uint4 stores).
// ---------------------------------------------------------------------------
__global__ __launch_bounds__(256) void scan_c_k(
    const unsigned* __restrict__ cnts,
    const unsigned* __restrict__ blkoff,
    unsigned* __restrict__ offs,
    unsigned* __restrict__ curs)
{
    __shared__ unsigned ps[256];
    int t    = threadIdx.x;
    int base = blockIdx.x * TILE + t * 4;
    unsigned v0 = 0, v1 = 0, v2 = 0, v3 = 0;
    if (base + 3 < NN) {
        uint4 u = *reinterpret_cast<const uint4*>(cnts + base);
        v0 = u.x; v1 = u.y; v2 = u.z; v3 = u.w;
    } else {
        if (base     < NN) v0 = cnts[base];
        if (base + 1 < NN) v1 = cnts[base + 1];
        if (base + 2 < NN) v2 = cnts[base + 2];
    }
    ps[t] = v0 + v1 + v2 + v3;
    __syncthreads();
    for (int off = 1; off < 256; off <<= 1) {
        unsigned u = (t >= off) ? ps[t - off] : 0u;
        __syncthreads();
        ps[t] += u;
        __syncthreads();
    }
    unsigned run = blkoff[blockIdx.x] + ((t == 0) ? 0u : ps[t - 1]);
    unsigned o0 = run, o1 = o0 + v0, o2 = o1 + v1, o3 = o2 + v2;
    if (base + 3 < NN) {
        *reinterpret_cast<uint4*>(offs + base) = make_uint4(o0, o1, o2, o3);
        *reinterpret_cast<uint4*>(curs + base) = make_uint4(o0, o1, o2, o3);
    } else {
        if (base     < NN) { offs[base]     = o0; curs[base]     = o0; }
        if (base + 1 < NN) { offs[base + 1] = o1; curs[base + 1] = o1; }
        if (base + 2 < NN) { offs[base + 2] = o2; curs[base + 2] = o2; }
    }
}

// ---------------------------------------------------------------------------
// 3) Bin edges by target: esrc[slot] = src.
// ---------------------------------------------------------------------------
__global__ __launch_bounds__(256) void bin_k(
    const int* __restrict__ ei,
    unsigned* __restrict__ curs,
    int* __restrict__ esrc)
{
    int e = blockIdx.x * 256 + threadIdx.x;
    if (e >= NE) return;
    int s = ei[e];
    int t = ei[NE + e];
    if ((unsigned)s >= NN || (unsigned)t >= NN) return;
    unsigned pos = atomicAdd(&curs[t], 1u);
    esrc[pos] = s;
}

// ---------------------------------------------------------------------------
// 4) Fused mean + linear + residual:
//    out[n] = x[n] + b + (mean over CSR segment of x[src]) @ W^T
//    LDS trimmed for occupancy: Ws[32][132] 16.9 KB (4 chunks of W) +
//    mean_s[32][132] 16.9 KB = 33.8 KB -> 4 blocks/CU (16 waves, 50%).
// ---------------------------------------------------------------------------
__global__ __launch_bounds__(256) void fused_k(
    const float* __restrict__ x,
    const float* __restrict__ W,        // [o][i] row-major, 128x128
    const float* __restrict__ b,
    const unsigned* __restrict__ offs,
    const int* __restrict__ esrc,
    float* __restrict__ out)
{
    __shared__ float Ws[WCH][DIM + PAD];      // Ws[il][o] = W[o][c*WCH+il]
    __shared__ float mean_s[NPT][DIM + PAD];

    const int t    = threadIdx.x;
    const int base = blockIdx.x * NPT;

    // Compute 32 mean rows directly: 8 threads/node, 16 floats each.
    // One-ahead esrc prefetch breaks the index->address serial chain.
    {
        int sn   = t >> 3;
        int so   = (t & 7) * 16;
        int node = base + sn;
        unsigned beg = offs[node], end = offs[node + 1];
        float4 a0 = make_float4(0.f, 0.f, 0.f, 0.f), a1 = a0, a2 = a0, a3 = a0;
        int s = (beg < end) ? esrc[beg] : 0;
        for (unsigned j = beg; j < end; ++j) {
            int snext = (j + 1 < end) ? esrc[j + 1] : 0;
            const float4* xr = reinterpret_cast<const float4*>(x + (size_t)s * DIM + so);
            float4 g0 = xr[0], g1 = xr[1], g2 = xr[2], g3 = xr[3];
            a0.x += g0.x; a0.y += g0.y; a0.z += g0.z; a0.w += g0.w;
            a1.x += g1.x; a1.y += g1.y; a1.z += g1.z; a1.w += g1.w;
            a2.x += g2.x; a2.y += g2.y; a2.z += g2.z; a2.w += g2.w;
            a3.x += g3.x; a3.y += g3.y; a3.z += g3.z; a3.w += g3.w;
            s = snext;
        }
        float inv = 1.0f / fmaxf((float)(end - beg), 1.0f);
        a0.x *= inv; a0.y *= inv; a0.z *= inv; a0.w *= inv;
        a1.x *= inv; a1.y *= inv; a1.z *= inv; a1.w *= inv;
        a2.x *= inv; a2.y *= inv; a2.z *= inv; a2.w *= inv;
        a3.x *= inv; a3.y *= inv; a3.z *= inv; a3.w *= inv;
        *reinterpret_cast<float4*>(&mean_s[sn][so +  0]) = a0;
        *reinterpret_cast<float4*>(&mean_s[sn][so +  4]) = a1;
        *reinterpret_cast<float4*>(&mean_s[sn][so +  8]) = a2;
        *reinterpret_cast<float4*>(&mean_s[sn][so + 12]) = a3;
    }

    const int og = (t & 31) * 4;    // 4 consecutive outputs per thread
    const int ng = (t >> 5) * 4;    // 4 consecutive nodes per thread

    float4 acc[4];
    #pragma unroll
    for (int n = 0; n < 4; ++n) acc[n] = make_float4(0.f, 0.f, 0.f, 0.f);

    for (int c = 0; c < DIM / WCH; ++c) {
        __syncthreads();   // (c=0: also covers mean_s staging)
        // Stage W chunk transposed: 4096 elements, coalesced global reads
        #pragma unroll
        for (int k = 0; k < (DIM * WCH) / 256; ++k) {
            int idx = t + k * 256;      // 0..4095
            int o   = idx >> 5;         // 0..127
            int il  = idx & 31;         // 0..31
            Ws[il][o] = W[o * DIM + c * WCH + il];
        }
        __syncthreads();

        #pragma unroll
        for (int i = 0; i < WCH; i += 4) {
            float4 m4[4];
            #pragma unroll
            for (int n = 0; n < 4; ++n)
                m4[n] = *reinterpret_cast<const float4*>(&mean_s[ng + n][c * WCH + i]);
            #pragma unroll
            for (int j = 0; j < 4; ++j) {
                float4 w = *reinterpret_cast<const float4*>(&Ws[i + j][og]);
                #pragma unroll
                for (int n = 0; n < 4; ++n) {
                    float m = (j == 0) ? m4[n].x : (j == 1) ? m4[n].y
                            : (j == 2) ? m4[n].z : m4[n].w;
                    acc[n].x += m * w.x;
                    acc[n].y += m * w.y;
                    acc[n].z += m * w.z;
                    acc[n].w += m * w.w;
                }
            }
        }
    }

    float4 bv = *reinterpret_cast<const float4*>(b + og);
    #pragma unroll
    for (int n = 0; n < 4; ++n) {
        int node = base + ng + n;
        float4 xv = *reinterpret_cast<const float4*>(x + (size_t)node * DIM + og);
        float4 o4;
        o4.x = xv.x + bv.x + acc[n].x;
        o4.y = xv.y + bv.y + acc[n].y;
        o4.z = xv.z + bv.z + acc[n].z;
        o4.w = xv.w + bv.w + acc[n].w;
        *reinterpret_cast<float4*>(out + (size_t)node * DIM + og) = o4;
    }
}

extern "C" void kernel_launch(void* const* d_in, const int* in_sizes, int n_in,
                              void* d_out, int out_size, void* d_ws, size_t ws_size,
                              hipStream_t stream) {
    const float* x  = (const float*)d_in[0];
    const int*   ei = (const int*)d_in[1];     // int32 per harness contract
    const float* W  = (const float*)d_in[2];
    const float* b  = (const float*)d_in[3];
    float* out = (float*)d_out;

    unsigned* cnts   = (unsigned*)d_ws;
    unsigned* offs   = cnts + NN;              // NN+1 used (padded to NN+4)
    unsigned* curs   = cnts + 2 * NN + 4;      // NN
    int*      esrc   = (int*)(cnts + 3 * NN + 4);   // NE
    unsigned* blksum = (unsigned*)(esrc + NE);      // 128
    unsigned* blkoff = blksum + 128;                // 128

    hipMemsetAsync(cnts, 0, (size_t)NN * sizeof(unsigned), stream);

    hist_k  <<<(NE + 255) / 256, 256, 0, stream>>>(ei, cnts);
    scan_a_k<<<NBLK, 256, 0, stream>>>(cnts, blksum);
    scan_b_k<<<1, 128, 0, stream>>>(blksum, blkoff, offs);
    scan_c_k<<<NBLK, 256, 0, stream>>>(cnts, blkoff, offs, curs);
    bin_k   <<<(NE + 255) / 256, 256, 0, stream>>>(ei, curs, esrc);
    fused_k <<<NN / NPT, 256, 0, stream>>>(x, W, b, offs, esrc, out);
}